// Round 5
// baseline (287.313 us; speedup 1.0000x reference)
//
#include <hip/hip_runtime.h>
#include <hip/hip_bf16.h>

#define M_DIM 16384
#define IN_DIM 512
#define H_DIM 1024
#define BH (M_DIM * H_DIM)

typedef float f32x4 __attribute__((ext_vector_type(4)));
typedef short bf16x8 __attribute__((ext_vector_type(8)));

// ---------------- bf16 helpers ----------------
static __device__ __forceinline__ unsigned short f2bf(float f) {
    union { float f; unsigned u; } a; a.f = f;
    unsigned r = a.u + 0x7fffu + ((a.u >> 16) & 1u);  // RNE
    return (unsigned short)(r >> 16);
}
static __device__ __forceinline__ float bf2f(unsigned short u) {
    union { unsigned u; float f; } a; a.u = (unsigned)u << 16;
    return a.f;
}

// ===================================================================
// ws layout (bf16 elements)
// ===================================================================
#define OFF_HB   0u                       // 16384x1024
#define OFF_XB   16777216u                // 16384x512
#define OFF_WU   25165824u                // 1024x1024
#define OFF_WHX  26214400u                // 1024x512
#define OFF_WHH  26738688u                // 1024x1024
#define OFF_WR   27787264u                // 1024x1024
#define OFF_RH   28835840u                // 16384x1024
#define WS_ELEMS 45613056u
#define WS_NEED_BYTES (WS_ELEMS * 2ull)
#define OFF_U    WS_ELEMS                 // 16384x1024 bf16 (optional)
#define WS2_ELEMS (WS_ELEMS + 16777216u)
#define WS2_NEED_BYTES (WS2_ELEMS * 2ull)

// One-pass fp32 -> bf16 conversion of all operands. Unit = 8 floats.
__global__ __launch_bounds__(256) void k_conv(const float* __restrict__ x,
                                              const float* __restrict__ h,
                                              const float* __restrict__ wu,
                                              const float* __restrict__ whx,
                                              const float* __restrict__ whh,
                                              const float* __restrict__ wr,
                                              unsigned short* __restrict__ ws) {
    const int total = 3604480;  // total 8-elem units
    for (int u = blockIdx.x * blockDim.x + threadIdx.x; u < total;
         u += gridDim.x * blockDim.x) {
        const float* src; unsigned short* dst; int lu;
        if (u < 2097152)      { src = h;   dst = ws + OFF_HB;  lu = u; }
        else if (u < 3145728) { src = x;   dst = ws + OFF_XB;  lu = u - 2097152; }
        else if (u < 3276800) { src = wu;  dst = ws + OFF_WU;  lu = u - 3145728; }
        else if (u < 3342336) { src = whx; dst = ws + OFF_WHX; lu = u - 3276800; }
        else if (u < 3473408) { src = whh; dst = ws + OFF_WHH; lu = u - 3342336; }
        else                  { src = wr;  dst = ws + OFF_WR;  lu = u - 3473408; }
        float4 a = reinterpret_cast<const float4*>(src)[lu * 2];
        float4 b = reinterpret_cast<const float4*>(src)[lu * 2 + 1];
        uint4 p;
        p.x = (unsigned)f2bf(a.x) | ((unsigned)f2bf(a.y) << 16);
        p.y = (unsigned)f2bf(a.z) | ((unsigned)f2bf(a.w) << 16);
        p.z = (unsigned)f2bf(b.x) | ((unsigned)f2bf(b.y) << 16);
        p.w = (unsigned)f2bf(b.z) | ((unsigned)f2bf(b.w) << 16);
        reinterpret_cast<uint4*>(dst)[lu] = p;
    }
}

// ===================================================================
// 256x256 8-wave phase-split GEMM machinery
// ===================================================================
// Stage one 128x64 half-tile (16 KB) into linear LDS via global_load_lds w=16.
// Chunk-column involution kc ^ (row&7) on the GLOBAL side (rule #21); ds_read
// applies the same XOR. 2 loads/thread (512 threads).
static __device__ __forceinline__ void stage_half(const unsigned short* __restrict__ src,
                                                  int rowBase, int ld, int ks,
                                                  unsigned short* lds, int tid) {
#pragma unroll
    for (int i = 0; i < 2; ++i) {
        int c = i * 512 + tid;            // 16B-chunk id in [0,1024): 128 rows x 8 chunks
        int r = c >> 3, kc = c & 7;
        int gc = kc ^ (r & 7);            // involution
        const unsigned short* g = src + (size_t)(rowBase + r) * ld + ks + gc * 8;
        __builtin_amdgcn_global_load_lds((const __attribute__((address_space(1))) void*)g,
                                         (__attribute__((address_space(3))) void*)(lds + c * 8),
                                         16, 0, 0);
    }
}

// Core K-loop: consume buf t&1, stage tile t+1 into buf (t&1)^1 at phases 0-1,
// single vmcnt(0) at group tail. 4 phases/K-tile, 16 MFMA each, setprio-wrapped.
// acc[8][4]: per-wave 128x64 output. Stage sources resolved by caller lambdas.
#define GEMM_LOOP(NT, STAGE_A, STAGE_B)                                                   \
    for (int t = 0; t < (NT); ++t) {                                                      \
        int b = t & 1;                                                                    \
        const unsigned short* Ab = As + b * 16384;                                        \
        const unsigned short* Bb = Bs + b * 16384;                                        \
        unsigned short* An = As + (b ^ 1) * 16384;                                        \
        unsigned short* Bn = Bs + (b ^ 1) * 16384;                                        \
        bool doStage = (t + 1 < (NT));                                                    \
        bf16x8 bv[4][2];                                                                  \
        _Pragma("unroll")                                                                 \
        for (int q = 0; q < 4; ++q) {                                                     \
            bf16x8 av[2][2];                                                              \
            if (q == 0) {                                                                 \
                _Pragma("unroll")                                                         \
                for (int n = 0; n < 4; ++n)                                               \
                    _Pragma("unroll")                                                     \
                    for (int kk = 0; kk < 2; ++kk)                                        \
                        bv[n][kk] = *reinterpret_cast<const bf16x8*>(                     \
                            &Bb[boff + n * 1024 + kc8[kk]]);                              \
            }                                                                             \
            _Pragma("unroll")                                                             \
            for (int mi = 0; mi < 2; ++mi)                                                \
                _Pragma("unroll")                                                         \
                for (int kk = 0; kk < 2; ++kk)                                            \
                    av[mi][kk] = *reinterpret_cast<const bf16x8*>(                        \
                        &Ab[aoff + (q * 2 + mi) * 1024 + kc8[kk]]);                       \
            if (q == 0 && doStage) { STAGE_A(t + 1, An); }                                \
            if (q == 1 && doStage) { STAGE_B(t + 1, Bn); }                                \
            __builtin_amdgcn_s_barrier();                                                 \
            __builtin_amdgcn_s_setprio(1);                                                \
            _Pragma("unroll")                                                             \
            for (int kk = 0; kk < 2; ++kk)                                                \
                _Pragma("unroll")                                                         \
                for (int mi = 0; mi < 2; ++mi)                                            \
                    _Pragma("unroll")                                                     \
                    for (int n = 0; n < 4; ++n)                                           \
                        acc[q * 2 + mi][n] = __builtin_amdgcn_mfma_f32_16x16x32_bf16(     \
                            av[mi][kk], bv[n][kk], acc[q * 2 + mi][n], 0, 0, 0);          \
            __builtin_amdgcn_s_setprio(0);                                                \
            if (q == 3) asm volatile("s_waitcnt vmcnt(0)" ::: "memory");                  \
            __builtin_amdgcn_s_barrier();                                                 \
        }                                                                                 \
    }

// Gates GEMM: concat B-panel (W_r | W_u), K=1024, N=2048. BN=256 -> bn 0..7.
__global__ __launch_bounds__(512, 2) void k_gates_b(const unsigned short* __restrict__ hb,
                                                    const unsigned short* __restrict__ wrb,
                                                    const unsigned short* __restrict__ wub,
                                                    const float* __restrict__ b_r,
                                                    const float* __restrict__ b_u,
                                                    unsigned short* __restrict__ rh,
                                                    unsigned short* __restrict__ u16,
                                                    float* __restrict__ uf32,
                                                    int useU16) {
    __shared__ unsigned short As[2 * 16384];   // [buf][half*8192 + r*64 + c]
    __shared__ unsigned short Bs[2 * 16384];

    int bid = blockIdx.x;
    int swz = (bid & 7) * 64 + (bid >> 3);     // bijective XCD swizzle, nwg=512
    int bm = swz >> 3, bn = swz & 7;
    bool isR = bn < 4;
    const unsigned short* wsrc = isR ? wrb : wub;
    const float* bias = isR ? b_r : b_u;
    int bnn = bn & 3;

    int tid = threadIdx.x;
    int wave = tid >> 6, lane = tid & 63;
    int wm = wave >> 2, wn = wave & 3;         // 2 x 4 waves
    int frow = lane & 15, klane = lane >> 4;

    int kc8[2];
    kc8[0] = (klane ^ (frow & 7)) * 8;
    kc8[1] = ((4 + klane) ^ (frow & 7)) * 8;
    int aoff = wm * 8192 + frow * 64;
    int boff = (wn >> 1) * 8192 + (wn & 1) * 4096 + frow * 64;

    f32x4 acc[8][4] = {};

    auto stA = [&](int kt, unsigned short* L) {
        stage_half(hb, bm * 256,       H_DIM, kt * 64, L, tid);
        stage_half(hb, bm * 256 + 128, H_DIM, kt * 64, L + 8192, tid);
    };
    auto stB = [&](int kt, unsigned short* L) {
        stage_half(wsrc, bnn * 256,       H_DIM, kt * 64, L, tid);
        stage_half(wsrc, bnn * 256 + 128, H_DIM, kt * 64, L + 8192, tid);
    };

    // prologue: tile 0 -> buf 0
    stA(0, As); stB(0, Bs);
    asm volatile("s_waitcnt vmcnt(0)" ::: "memory");
    __builtin_amdgcn_s_barrier();

    GEMM_LOOP(16, stA, stB)

    int rbase = bm * 256 + wm * 128;
    int cbase = bnn * 256 + wn * 64;
#pragma unroll
    for (int m = 0; m < 8; ++m) {
#pragma unroll
        for (int n = 0; n < 4; ++n) {
            int col = cbase + n * 16 + frow;
            float bs = bias[col];
#pragma unroll
            for (int q = 0; q < 4; ++q) {
                int row = rbase + m * 16 + klane * 4 + q;
                size_t off = (size_t)row * H_DIM + col;
                float g = 1.0f / (1.0f + __expf(-(acc[m][n][q] + bs)));
                if (isR)          rh[off] = f2bf(g * bf2f(hb[off]));
                else if (useU16)  u16[off] = f2bf(g);
                else              uf32[off] = g;
            }
        }
    }
}

// Candidate GEMM + blend: virtual 24-tile K (8 of x@Whx^T, 16 of rh@Whh^T).
__global__ __launch_bounds__(512, 2) void k_cand_b(const unsigned short* __restrict__ xb,
                                                   const unsigned short* __restrict__ whxb,
                                                   const unsigned short* __restrict__ rh,
                                                   const unsigned short* __restrict__ whhb,
                                                   const unsigned short* __restrict__ hb,
                                                   const float* __restrict__ b_h,
                                                   const unsigned short* __restrict__ u16,
                                                   const float* __restrict__ uf32,
                                                   int useU16,
                                                   float* __restrict__ out) {
    __shared__ unsigned short As[2 * 16384];
    __shared__ unsigned short Bs[2 * 16384];

    int bid = blockIdx.x;
    int swz = (bid & 7) * 32 + (bid >> 3);     // bijective XCD swizzle, nwg=256
    int bm = swz >> 2, bn = swz & 3;

    int tid = threadIdx.x;
    int wave = tid >> 6, lane = tid & 63;
    int wm = wave >> 2, wn = wave & 3;
    int frow = lane & 15, klane = lane >> 4;

    int kc8[2];
    kc8[0] = (klane ^ (frow & 7)) * 8;
    kc8[1] = ((4 + klane) ^ (frow & 7)) * 8;
    int aoff = wm * 8192 + frow * 64;
    int boff = (wn >> 1) * 8192 + (wn & 1) * 4096 + frow * 64;

    f32x4 acc[8][4] = {};

    auto stA = [&](int kt, unsigned short* L) {
        if (kt < 8) {
            stage_half(xb, bm * 256,       IN_DIM, kt * 64, L, tid);
            stage_half(xb, bm * 256 + 128, IN_DIM, kt * 64, L + 8192, tid);
        } else {
            stage_half(rh, bm * 256,       H_DIM, (kt - 8) * 64, L, tid);
            stage_half(rh, bm * 256 + 128, H_DIM, (kt - 8) * 64, L + 8192, tid);
        }
    };
    auto stB = [&](int kt, unsigned short* L) {
        if (kt < 8) {
            stage_half(whxb, bn * 256,       IN_DIM, kt * 64, L, tid);
            stage_half(whxb, bn * 256 + 128, IN_DIM, kt * 64, L + 8192, tid);
        } else {
            stage_half(whhb, bn * 256,       H_DIM, (kt - 8) * 64, L, tid);
            stage_half(whhb, bn * 256 + 128, H_DIM, (kt - 8) * 64, L + 8192, tid);
        }
    };

    stA(0, As); stB(0, Bs);
    asm volatile("s_waitcnt vmcnt(0)" ::: "memory");
    __builtin_amdgcn_s_barrier();

    GEMM_LOOP(24, stA, stB)

    int rbase = bm * 256 + wm * 128;
    int cbase = bn * 256 + wn * 64;
#pragma unroll
    for (int m = 0; m < 8; ++m) {
#pragma unroll
        for (int n = 0; n < 4; ++n) {
            int col = cbase + n * 16 + frow;
            float bh = b_h[col];
#pragma unroll
            for (int q = 0; q < 4; ++q) {
                int row = rbase + m * 16 + klane * 4 + q;
                size_t off = (size_t)row * H_DIM + col;
                float hp = bf2f(hb[off]);
                float u = useU16 ? bf2f(u16[off]) : uf32[off];
                float cpre = acc[m][n][q] + bh;
                cpre = fminf(fmaxf(cpre, -15.0f), 15.0f);
                float e = __expf(2.0f * cpre);
                float c = (e - 1.0f) / (e + 1.0f);
                float h = hp + u * (c - hp);
                out[off] = h;
                out[BH + off] = h;
            }
        }
    }
}

// ===================================================================
// FALLBACK PATH (round-1 kernels, fp32 reg-staged) — used if ws too small
// ===================================================================
#define LDSS 40

static __device__ __forceinline__ void stage_f32(const float* __restrict__ src, int rowBase,
                                                 int ld, int kBase,
                                                 unsigned short* lds, int tid) {
#pragma unroll
    for (int i = 0; i < 4; ++i) {
        int idx = i * 256 + tid;
        int r = idx >> 3, c4 = idx & 7;
        const float4 v = *reinterpret_cast<const float4*>(
            src + (size_t)(rowBase + r) * ld + kBase + c4 * 4);
        uint2 p;
        p.x = (unsigned)f2bf(v.x) | ((unsigned)f2bf(v.y) << 16);
        p.y = (unsigned)f2bf(v.z) | ((unsigned)f2bf(v.w) << 16);
        *reinterpret_cast<uint2*>(lds + r * LDSS + c4 * 4) = p;
    }
}

static __device__ __forceinline__ void stage_bf16s(const unsigned short* __restrict__ src,
                                                   int rowBase, int ld, int kBase,
                                                   unsigned short* lds, int tid) {
#pragma unroll
    for (int i = 0; i < 2; ++i) {
        int idx = i * 256 + tid;
        int r = idx >> 2, c8 = idx & 3;
        const uint4 v = *reinterpret_cast<const uint4*>(
            src + (size_t)(rowBase + r) * ld + kBase + c8 * 8);
        *reinterpret_cast<uint4*>(lds + r * LDSS + c8 * 8) = v;
    }
}

__global__ __launch_bounds__(256, 2) void k_rgate(const float* __restrict__ h_prev,
                                                  const float* __restrict__ W_r,
                                                  const float* __restrict__ b_r,
                                                  unsigned short* __restrict__ rh) {
    __shared__ unsigned short As[128 * LDSS];
    __shared__ unsigned short Bs[128 * LDSS];
    int bid = blockIdx.x;
    int swz = (bid & 7) * 128 + (bid >> 3);
    int bm = swz >> 3, bn = swz & 7;
    int tid = threadIdx.x;
    int wave = tid >> 6, lane = tid & 63;
    int wm = wave >> 1, wn = wave & 1;
    int frow = lane & 15, koff = (lane >> 4) * 8;
    f32x4 acc[4][4] = {};
    for (int ks = 0; ks < H_DIM; ks += 32) {
        stage_f32(h_prev, bm * 128, H_DIM, ks, As, tid);
        stage_f32(W_r, bn * 128, H_DIM, ks, Bs, tid);
        __syncthreads();
        bf16x8 av[4], bv[4];
#pragma unroll
        for (int m = 0; m < 4; ++m)
            av[m] = *reinterpret_cast<const bf16x8*>(&As[(wm * 64 + m * 16 + frow) * LDSS + koff]);
#pragma unroll
        for (int n = 0; n < 4; ++n)
            bv[n] = *reinterpret_cast<const bf16x8*>(&Bs[(wn * 64 + n * 16 + frow) * LDSS + koff]);
#pragma unroll
        for (int m = 0; m < 4; ++m)
#pragma unroll
            for (int n = 0; n < 4; ++n)
                acc[m][n] = __builtin_amdgcn_mfma_f32_16x16x32_bf16(av[m], bv[n], acc[m][n], 0, 0, 0);
        __syncthreads();
    }
    int rbase = bm * 128 + wm * 64, cbase = bn * 128 + wn * 64;
#pragma unroll
    for (int m = 0; m < 4; ++m)
#pragma unroll
        for (int n = 0; n < 4; ++n) {
            int col = cbase + n * 16 + frow;
            float bias = b_r[col];
#pragma unroll
            for (int q = 0; q < 4; ++q) {
                int row = rbase + m * 16 + (lane >> 4) * 4 + q;
                float pre = acc[m][n][q] + bias;
                float rv = 1.0f / (1.0f + __expf(-pre));
                rh[(size_t)row * H_DIM + col] = f2bf(rv * h_prev[(size_t)row * H_DIM + col]);
            }
        }
}

__global__ __launch_bounds__(256, 2) void k_fused(const float* __restrict__ x,
                                                  const float* __restrict__ h_prev,
                                                  const float* __restrict__ W_u,
                                                  const float* __restrict__ b_u,
                                                  const float* __restrict__ W_hx,
                                                  const float* __restrict__ W_hh,
                                                  const float* __restrict__ b_h,
                                                  const unsigned short* __restrict__ rh,
                                                  float* __restrict__ out) {
    __shared__ unsigned short As[128 * LDSS];
    __shared__ unsigned short Bs[128 * LDSS];
    int bid = blockIdx.x;
    int swz = (bid & 7) * 128 + (bid >> 3);
    int bm = swz >> 3, bn = swz & 7;
    int tid = threadIdx.x;
    int wave = tid >> 6, lane = tid & 63;
    int wm = wave >> 1, wn = wave & 1;
    int frow = lane & 15, koff = (lane >> 4) * 8;
    f32x4 accu[4][4] = {};
    f32x4 accc[4][4] = {};
    for (int ks = 0; ks < H_DIM; ks += 32) {
        stage_f32(h_prev, bm * 128, H_DIM, ks, As, tid);
        stage_f32(W_u, bn * 128, H_DIM, ks, Bs, tid);
        __syncthreads();
        bf16x8 av[4], bv[4];
#pragma unroll
        for (int m = 0; m < 4; ++m)
            av[m] = *reinterpret_cast<const bf16x8*>(&As[(wm * 64 + m * 16 + frow) * LDSS + koff]);
#pragma unroll
        for (int n = 0; n < 4; ++n)
            bv[n] = *reinterpret_cast<const bf16x8*>(&Bs[(wn * 64 + n * 16 + frow) * LDSS + koff]);
#pragma unroll
        for (int m = 0; m < 4; ++m)
#pragma unroll
            for (int n = 0; n < 4; ++n)
                accu[m][n] = __builtin_amdgcn_mfma_f32_16x16x32_bf16(av[m], bv[n], accu[m][n], 0, 0, 0);
        __syncthreads();
    }
    for (int ks = 0; ks < IN_DIM; ks += 32) {
        stage_f32(x, bm * 128, IN_DIM, ks, As, tid);
        stage_f32(W_hx, bn * 128, IN_DIM, ks, Bs, tid);
        __syncthreads();
        bf16x8 av[4], bv[4];
#pragma unroll
        for (int m = 0; m < 4; ++m)
            av[m] = *reinterpret_cast<const bf16x8*>(&As[(wm * 64 + m * 16 + frow) * LDSS + koff]);
#pragma unroll
        for (int n = 0; n < 4; ++n)
            bv[n] = *reinterpret_cast<const bf16x8*>(&Bs[(wn * 64 + n * 16 + frow) * LDSS + koff]);
#pragma unroll
        for (int m = 0; m < 4; ++m)
#pragma unroll
            for (int n = 0; n < 4; ++n)
                accc[m][n] = __builtin_amdgcn_mfma_f32_16x16x32_bf16(av[m], bv[n], accc[m][n], 0, 0, 0);
        __syncthreads();
    }
    for (int ks = 0; ks < H_DIM; ks += 32) {
        stage_bf16s(rh, bm * 128, H_DIM, ks, As, tid);
        stage_f32(W_hh, bn * 128, H_DIM, ks, Bs, tid);
        __syncthreads();
        bf16x8 av[4], bv[4];
#pragma unroll
        for (int m = 0; m < 4; ++m)
            av[m] = *reinterpret_cast<const bf16x8*>(&As[(wm * 64 + m * 16 + frow) * LDSS + koff]);
#pragma unroll
        for (int n = 0; n < 4; ++n)
            bv[n] = *reinterpret_cast<const bf16x8*>(&Bs[(wn * 64 + n * 16 + frow) * LDSS + koff]);
#pragma unroll
        for (int m = 0; m < 4; ++m)
#pragma unroll
            for (int n = 0; n < 4; ++n)
                accc[m][n] = __builtin_amdgcn_mfma_f32_16x16x32_bf16(av[m], bv[n], accc[m][n], 0, 0, 0);
        __syncthreads();
    }
    int rbase = bm * 128 + wm * 64, cbase = bn * 128 + wn * 64;
#pragma unroll
    for (int m = 0; m < 4; ++m)
#pragma unroll
        for (int n = 0; n < 4; ++n) {
            int col = cbase + n * 16 + frow;
            float bu = b_u[col], bh = b_h[col];
#pragma unroll
            for (int q = 0; q < 4; ++q) {
                int row = rbase + m * 16 + (lane >> 4) * 4 + q;
                size_t off = (size_t)row * H_DIM + col;
                float hp = h_prev[off];
                float u = 1.0f / (1.0f + __expf(-(accu[m][n][q] + bu)));
                float cpre = accc[m][n][q] + bh;
                cpre = fminf(fmaxf(cpre, -15.0f), 15.0f);
                float e = __expf(2.0f * cpre);
                float c = (e - 1.0f) / (e + 1.0f);
                float h = hp + u * (c - hp);
                out[off] = h;
                out[BH + off] = h;
            }
        }
}

extern "C" void kernel_launch(void* const* d_in, const int* in_sizes, int n_in,
                              void* d_out, int out_size, void* d_ws, size_t ws_size,
                              hipStream_t stream) {
    const float* x      = (const float*)d_in[0];
    const float* h_prev = (const float*)d_in[1];
    const float* W_u    = (const float*)d_in[2];
    const float* b_u    = (const float*)d_in[3];
    const float* W_r    = (const float*)d_in[4];
    const float* b_r    = (const float*)d_in[5];
    const float* W_hx   = (const float*)d_in[6];
    const float* W_hh   = (const float*)d_in[7];
    const float* b_h    = (const float*)d_in[8];
    float* out = (float*)d_out;

    if (ws_size >= WS_NEED_BYTES) {
        unsigned short* ws = (unsigned short*)d_ws;
        int useU16 = (ws_size >= WS2_NEED_BYTES) ? 1 : 0;
        unsigned short* u16 = ws + OFF_U;          // valid only if useU16
        float* uf32 = out + BH;                    // aliasing-safe f32 fallback
        hipLaunchKernelGGL(k_conv, dim3(2048), dim3(256), 0, stream,
                           x, h_prev, W_u, W_hx, W_hh, W_r, ws);
        hipLaunchKernelGGL(k_gates_b, dim3(512), dim3(512), 0, stream,
                           ws + OFF_HB, ws + OFF_WR, ws + OFF_WU, b_r, b_u,
                           ws + OFF_RH, u16, uf32, useU16);
        hipLaunchKernelGGL(k_cand_b, dim3(256), dim3(512), 0, stream,
                           ws + OFF_XB, ws + OFF_WHX, ws + OFF_RH, ws + OFF_WHH,
                           ws + OFF_HB, b_h, u16, uf32, useU16, out);
    } else {
        unsigned short* rh = (unsigned short*)d_ws;
        hipLaunchKernelGGL(k_rgate, dim3(1024), dim3(256), 0, stream, h_prev, W_r, b_r, rh);
        hipLaunchKernelGGL(k_fused, dim3(1024), dim3(256), 0, stream,
                           x, h_prev, W_u, b_u, W_hx, W_hh, b_h, rh, out);
    }
}

// Round 6
// 206.624 us; speedup vs baseline: 1.3905x; 1.3905x over previous
//
#include <hip/hip_runtime.h>
#include <hip/hip_bf16.h>

#define M_DIM 16384
#define IN_DIM 512
#define H_DIM 1024
#define BH (M_DIM * H_DIM)
#define K2 1536                            // fused K for cand: 512 (x) + 1024 (rh)

typedef float f32x4 __attribute__((ext_vector_type(4)));
typedef short bf16x8 __attribute__((ext_vector_type(8)));

// ---------------- bf16 helpers ----------------
static __device__ __forceinline__ unsigned short f2bf(float f) {
    union { float f; unsigned u; } a; a.f = f;
    unsigned r = a.u + 0x7fffu + ((a.u >> 16) & 1u);  // RNE
    return (unsigned short)(r >> 16);
}
static __device__ __forceinline__ float bf2f(unsigned short u) {
    union { unsigned u; float f; } a; a.u = (unsigned)u << 16;
    return a.f;
}

// ===================================================================
// ws layout (bf16 elements), total 124.78 MB
// ===================================================================
#define OFF_HB   0u                        // 16384x1024
#define OFF_A2   16777216u                 // 16384x1536: cols 0-511 = x, 512-1535 = rh
#define OFF_WU   41943040u                 // 1024x1024
#define OFF_WR   42991616u                 // 1024x1024
#define OFF_W2   44040192u                 // 1024x1536: cols 0-511 = W_hx, 512-1535 = W_hh
#define OFF_U16  45613056u                 // 16384x1024
#define WS2_ELEMS 62390272u
#define WS2_NEED_BYTES (WS2_ELEMS * 2ull)

// One-pass fp32 -> bf16 conversion of all operands into the fused layout.
__global__ __launch_bounds__(256) void k_conv(const float* __restrict__ x,
                                              const float* __restrict__ h,
                                              const float* __restrict__ wu,
                                              const float* __restrict__ whx,
                                              const float* __restrict__ whh,
                                              const float* __restrict__ wr,
                                              unsigned short* __restrict__ ws) {
    const int total = 3604480;  // total 8-elem units
    for (int u = blockIdx.x * blockDim.x + threadIdx.x; u < total;
         u += gridDim.x * blockDim.x) {
        const float* src; unsigned short* d; int lu;
        if (u < 2097152)      { lu = u;
                                src = h + (size_t)lu * 8;
                                d = ws + OFF_HB + (size_t)lu * 8; }
        else if (u < 3145728) { lu = u - 2097152;                       // x -> A2 strided
                                src = x + (size_t)lu * 8;
                                d = ws + OFF_A2 + (size_t)(lu >> 6) * K2 + (lu & 63) * 8; }
        else if (u < 3276800) { lu = u - 3145728;
                                src = wu + (size_t)lu * 8;
                                d = ws + OFF_WU + (size_t)lu * 8; }
        else if (u < 3342336) { lu = u - 3276800;                       // whx -> W2 strided
                                src = whx + (size_t)lu * 8;
                                d = ws + OFF_W2 + (size_t)(lu >> 6) * K2 + (lu & 63) * 8; }
        else if (u < 3473408) { lu = u - 3342336;                       // whh -> W2 + 512
                                src = whh + (size_t)lu * 8;
                                d = ws + OFF_W2 + (size_t)(lu >> 7) * K2 + 512 + (lu & 127) * 8; }
        else                  { lu = u - 3473408;
                                src = wr + (size_t)lu * 8;
                                d = ws + OFF_WR + (size_t)lu * 8; }
        float4 a = *reinterpret_cast<const float4*>(src);
        float4 b = *reinterpret_cast<const float4*>(src + 4);
        uint4 p;
        p.x = (unsigned)f2bf(a.x) | ((unsigned)f2bf(a.y) << 16);
        p.y = (unsigned)f2bf(a.z) | ((unsigned)f2bf(a.w) << 16);
        p.z = (unsigned)f2bf(b.x) | ((unsigned)f2bf(b.y) << 16);
        p.w = (unsigned)f2bf(b.z) | ((unsigned)f2bf(b.w) << 16);
        *reinterpret_cast<uint4*>(d) = p;
    }
}

// Stage a 128x64 bf16 tile into linear LDS via global_load_lds width-16, with the
// chunk-column involution kc ^ (row&7) applied on the GLOBAL side (rule #21).
static __device__ __forceinline__ void stage_lds(const unsigned short* __restrict__ src,
                                                 int rowBase, int ld, int ks,
                                                 unsigned short* lds, int tid) {
#pragma unroll
    for (int i = 0; i < 4; ++i) {
        int c = i * 256 + tid;           // 16B-chunk id in [0,1024): 128 rows x 8 chunks
        int r = c >> 3, kc = c & 7;
        int gc = kc ^ (r & 7);           // involution
        const unsigned short* g = src + (size_t)(rowBase + r) * ld + ks + gc * 8;
        unsigned short* l = lds + c * 8;
        __builtin_amdgcn_global_load_lds((const __attribute__((address_space(1))) void*)g,
                                         (__attribute__((address_space(3))) void*)l,
                                         16, 0, 0);
    }
}

// One GEMM segment (proven r3 structure): C[128x128] += A x B^T, BK=64.
template <int KSEG>
static __device__ __forceinline__ void gemm_seg(const unsigned short* __restrict__ A, int aLd,
                                                const unsigned short* __restrict__ B, int bLd,
                                                int bm, int bn,
                                                unsigned short* As, unsigned short* Bs,
                                                int tid, int wm, int wn, int frow, int klane,
                                                f32x4 acc[4][4]) {
    for (int ks = 0; ks < KSEG; ks += 64) {
        stage_lds(A, bm * 128, aLd, ks, As, tid);
        stage_lds(B, bn * 128, bLd, ks, Bs, tid);
        __syncthreads();
#pragma unroll
        for (int kk = 0; kk < 2; ++kk) {
            bf16x8 av[4], bv[4];
#pragma unroll
            for (int m = 0; m < 4; ++m) {
                int pr = wm * 64 + m * 16 + frow;
                av[m] = *reinterpret_cast<const bf16x8*>(
                    &As[pr * 64 + (((kk << 2) + klane) ^ (pr & 7)) * 8]);
            }
#pragma unroll
            for (int n = 0; n < 4; ++n) {
                int pr = wn * 64 + n * 16 + frow;
                bv[n] = *reinterpret_cast<const bf16x8*>(
                    &Bs[pr * 64 + (((kk << 2) + klane) ^ (pr & 7)) * 8]);
            }
#pragma unroll
            for (int m = 0; m < 4; ++m)
#pragma unroll
                for (int n = 0; n < 4; ++n)
                    acc[m][n] = __builtin_amdgcn_mfma_f32_16x16x32_bf16(av[m], bv[n], acc[m][n], 0, 0, 0);
        }
        __syncthreads();
    }
}

// Gates GEMM: concat B-panel (W_r | W_u), K=1024, N=2048.
// bn<8 -> r-block: rh (strided into A2 col 512+). bn>=8 -> u-block: u16.
__global__ __launch_bounds__(256, 3) void k_gates_b(const unsigned short* __restrict__ hb,
                                                    const unsigned short* __restrict__ wrb,
                                                    const unsigned short* __restrict__ wub,
                                                    const float* __restrict__ b_r,
                                                    const float* __restrict__ b_u,
                                                    unsigned short* __restrict__ rhA2,
                                                    unsigned short* __restrict__ u16) {
    __shared__ unsigned short As[128 * 64];
    __shared__ unsigned short Bs[128 * 64];

    int bid = blockIdx.x;
    int swz = (bid & 7) * 256 + (bid >> 3);   // bijective XCD swizzle, nwg=2048
    int bm = swz >> 4, bn = swz & 15;
    bool isR = bn < 8;
    const unsigned short* wsrc = isR ? wrb : wub;
    const float* bias = isR ? b_r : b_u;
    int bnn = bn & 7;

    int tid = threadIdx.x;
    int wave = tid >> 6, lane = tid & 63;
    int wm = wave >> 1, wn = wave & 1;
    int frow = lane & 15, klane = lane >> 4;

    f32x4 acc[4][4] = {};
    gemm_seg<H_DIM>(hb, H_DIM, wsrc, H_DIM, bm, bnn, As, Bs, tid, wm, wn, frow, klane, acc);

    int rbase = bm * 128 + wm * 64;
    int cbase = bnn * 128 + wn * 64;
#pragma unroll
    for (int m = 0; m < 4; ++m) {
#pragma unroll
        for (int n = 0; n < 4; ++n) {
            int col = cbase + n * 16 + frow;
            float bs = bias[col];
#pragma unroll
            for (int q = 0; q < 4; ++q) {
                int row = rbase + m * 16 + klane * 4 + q;
                size_t off = (size_t)row * H_DIM + col;
                float g = 1.0f / (1.0f + __expf(-(acc[m][n][q] + bs)));
                if (isR) rhA2[(size_t)row * K2 + col] = f2bf(g * bf2f(hb[off]));
                else     u16[off] = f2bf(g);
            }
        }
    }
}

// Candidate GEMM + blend: single segment, A2=[x|rh] (ld 1536) x W2=[Whx|Whh]^T.
__global__ __launch_bounds__(256, 3) void k_cand_b(const unsigned short* __restrict__ a2,
                                                   const unsigned short* __restrict__ w2,
                                                   const unsigned short* __restrict__ hb,
                                                   const unsigned short* __restrict__ u16,
                                                   const float* __restrict__ b_h,
                                                   float* __restrict__ out) {
    __shared__ unsigned short As[128 * 64];
    __shared__ unsigned short Bs[128 * 64];

    int bid = blockIdx.x;
    int swz = (bid & 7) * 128 + (bid >> 3);   // bijective XCD swizzle, nwg=1024
    int bm = swz >> 3, bn = swz & 7;

    int tid = threadIdx.x;
    int wave = tid >> 6, lane = tid & 63;
    int wm = wave >> 1, wn = wave & 1;
    int frow = lane & 15, klane = lane >> 4;

    f32x4 acc[4][4] = {};
    gemm_seg<K2>(a2, K2, w2, K2, bm, bn, As, Bs, tid, wm, wn, frow, klane, acc);

    int rbase = bm * 128 + wm * 64;
    int cbase = bn * 128 + wn * 64;
#pragma unroll
    for (int m = 0; m < 4; ++m) {
#pragma unroll
        for (int n = 0; n < 4; ++n) {
            int col = cbase + n * 16 + frow;
            float bh = b_h[col];
#pragma unroll
            for (int q = 0; q < 4; ++q) {
                int row = rbase + m * 16 + klane * 4 + q;
                size_t off = (size_t)row * H_DIM + col;
                float hp = bf2f(hb[off]);
                float u = bf2f(u16[off]);
                float cpre = acc[m][n][q] + bh;
                cpre = fminf(fmaxf(cpre, -15.0f), 15.0f);
                float e = __expf(2.0f * cpre);
                float c = (e - 1.0f) / (e + 1.0f);
                float h = hp + u * (c - hp);
                out[off] = h;
                out[BH + off] = h;
            }
        }
    }
}

// ===================================================================
// FALLBACK PATH (round-1 kernels, fp32 reg-staged) — used if ws too small
// ===================================================================
#define LDSS 40

static __device__ __forceinline__ void stage_f32(const float* __restrict__ src, int rowBase,
                                                 int ld, int kBase,
                                                 unsigned short* lds, int tid) {
#pragma unroll
    for (int i = 0; i < 4; ++i) {
        int idx = i * 256 + tid;
        int r = idx >> 3, c4 = idx & 7;
        const float4 v = *reinterpret_cast<const float4*>(
            src + (size_t)(rowBase + r) * ld + kBase + c4 * 4);
        uint2 p;
        p.x = (unsigned)f2bf(v.x) | ((unsigned)f2bf(v.y) << 16);
        p.y = (unsigned)f2bf(v.z) | ((unsigned)f2bf(v.w) << 16);
        *reinterpret_cast<uint2*>(lds + r * LDSS + c4 * 4) = p;
    }
}

static __device__ __forceinline__ void stage_bf16s(const unsigned short* __restrict__ src,
                                                   int rowBase, int ld, int kBase,
                                                   unsigned short* lds, int tid) {
#pragma unroll
    for (int i = 0; i < 2; ++i) {
        int idx = i * 256 + tid;
        int r = idx >> 2, c8 = idx & 3;
        const uint4 v = *reinterpret_cast<const uint4*>(
            src + (size_t)(rowBase + r) * ld + kBase + c8 * 8);
        *reinterpret_cast<uint4*>(lds + r * LDSS + c8 * 8) = v;
    }
}

__global__ __launch_bounds__(256, 2) void k_rgate(const float* __restrict__ h_prev,
                                                  const float* __restrict__ W_r,
                                                  const float* __restrict__ b_r,
                                                  unsigned short* __restrict__ rh) {
    __shared__ unsigned short As[128 * LDSS];
    __shared__ unsigned short Bs[128 * LDSS];
    int bid = blockIdx.x;
    int swz = (bid & 7) * 128 + (bid >> 3);
    int bm = swz >> 3, bn = swz & 7;
    int tid = threadIdx.x;
    int wave = tid >> 6, lane = tid & 63;
    int wm = wave >> 1, wn = wave & 1;
    int frow = lane & 15, koff = (lane >> 4) * 8;
    f32x4 acc[4][4] = {};
    for (int ks = 0; ks < H_DIM; ks += 32) {
        stage_f32(h_prev, bm * 128, H_DIM, ks, As, tid);
        stage_f32(W_r, bn * 128, H_DIM, ks, Bs, tid);
        __syncthreads();
        bf16x8 av[4], bv[4];
#pragma unroll
        for (int m = 0; m < 4; ++m)
            av[m] = *reinterpret_cast<const bf16x8*>(&As[(wm * 64 + m * 16 + frow) * LDSS + koff]);
#pragma unroll
        for (int n = 0; n < 4; ++n)
            bv[n] = *reinterpret_cast<const bf16x8*>(&Bs[(wn * 64 + n * 16 + frow) * LDSS + koff]);
#pragma unroll
        for (int m = 0; m < 4; ++m)
#pragma unroll
            for (int n = 0; n < 4; ++n)
                acc[m][n] = __builtin_amdgcn_mfma_f32_16x16x32_bf16(av[m], bv[n], acc[m][n], 0, 0, 0);
        __syncthreads();
    }
    int rbase = bm * 128 + wm * 64, cbase = bn * 128 + wn * 64;
#pragma unroll
    for (int m = 0; m < 4; ++m)
#pragma unroll
        for (int n = 0; n < 4; ++n) {
            int col = cbase + n * 16 + frow;
            float bias = b_r[col];
#pragma unroll
            for (int q = 0; q < 4; ++q) {
                int row = rbase + m * 16 + (lane >> 4) * 4 + q;
                float pre = acc[m][n][q] + bias;
                float rv = 1.0f / (1.0f + __expf(-pre));
                rh[(size_t)row * H_DIM + col] = f2bf(rv * h_prev[(size_t)row * H_DIM + col]);
            }
        }
}

__global__ __launch_bounds__(256, 2) void k_fused(const float* __restrict__ x,
                                                  const float* __restrict__ h_prev,
                                                  const float* __restrict__ W_u,
                                                  const float* __restrict__ b_u,
                                                  const float* __restrict__ W_hx,
                                                  const float* __restrict__ W_hh,
                                                  const float* __restrict__ b_h,
                                                  const unsigned short* __restrict__ rh,
                                                  float* __restrict__ out) {
    __shared__ unsigned short As[128 * LDSS];
    __shared__ unsigned short Bs[128 * LDSS];
    int bid = blockIdx.x;
    int swz = (bid & 7) * 128 + (bid >> 3);
    int bm = swz >> 3, bn = swz & 7;
    int tid = threadIdx.x;
    int wave = tid >> 6, lane = tid & 63;
    int wm = wave >> 1, wn = wave & 1;
    int frow = lane & 15, koff = (lane >> 4) * 8;
    f32x4 accu[4][4] = {};
    f32x4 accc[4][4] = {};
    for (int ks = 0; ks < H_DIM; ks += 32) {
        stage_f32(h_prev, bm * 128, H_DIM, ks, As, tid);
        stage_f32(W_u, bn * 128, H_DIM, ks, Bs, tid);
        __syncthreads();
        bf16x8 av[4], bv[4];
#pragma unroll
        for (int m = 0; m < 4; ++m)
            av[m] = *reinterpret_cast<const bf16x8*>(&As[(wm * 64 + m * 16 + frow) * LDSS + koff]);
#pragma unroll
        for (int n = 0; n < 4; ++n)
            bv[n] = *reinterpret_cast<const bf16x8*>(&Bs[(wn * 64 + n * 16 + frow) * LDSS + koff]);
#pragma unroll
        for (int m = 0; m < 4; ++m)
#pragma unroll
            for (int n = 0; n < 4; ++n)
                accu[m][n] = __builtin_amdgcn_mfma_f32_16x16x32_bf16(av[m], bv[n], accu[m][n], 0, 0, 0);
        __syncthreads();
    }
    for (int ks = 0; ks < IN_DIM; ks += 32) {
        stage_f32(x, bm * 128, IN_DIM, ks, As, tid);
        stage_f32(W_hx, bn * 128, IN_DIM, ks, Bs, tid);
        __syncthreads();
        bf16x8 av[4], bv[4];
#pragma unroll
        for (int m = 0; m < 4; ++m)
            av[m] = *reinterpret_cast<const bf16x8*>(&As[(wm * 64 + m * 16 + frow) * LDSS + koff]);
#pragma unroll
        for (int n = 0; n < 4; ++n)
            bv[n] = *reinterpret_cast<const bf16x8*>(&Bs[(wn * 64 + n * 16 + frow) * LDSS + koff]);
#pragma unroll
        for (int m = 0; m < 4; ++m)
#pragma unroll
            for (int n = 0; n < 4; ++n)
                accc[m][n] = __builtin_amdgcn_mfma_f32_16x16x32_bf16(av[m], bv[n], accc[m][n], 0, 0, 0);
        __syncthreads();
    }
    for (int ks = 0; ks < H_DIM; ks += 32) {
        stage_bf16s(rh, bm * 128, H_DIM, ks, As, tid);
        stage_f32(W_hh, bn * 128, H_DIM, ks, Bs, tid);
        __syncthreads();
        bf16x8 av[4], bv[4];
#pragma unroll
        for (int m = 0; m < 4; ++m)
            av[m] = *reinterpret_cast<const bf16x8*>(&As[(wm * 64 + m * 16 + frow) * LDSS + koff]);
#pragma unroll
        for (int n = 0; n < 4; ++n)
            bv[n] = *reinterpret_cast<const bf16x8*>(&Bs[(wn * 64 + n * 16 + frow) * LDSS + koff]);
#pragma unroll
        for (int m = 0; m < 4; ++m)
#pragma unroll
            for (int n = 0; n < 4; ++n)
                accc[m][n] = __builtin_amdgcn_mfma_f32_16x16x32_bf16(av[m], bv[n], accc[m][n], 0, 0, 0);
        __syncthreads();
    }
    int rbase = bm * 128 + wm * 64, cbase = bn * 128 + wn * 64;
#pragma unroll
    for (int m = 0; m < 4; ++m)
#pragma unroll
        for (int n = 0; n < 4; ++n) {
            int col = cbase + n * 16 + frow;
            float bu = b_u[col], bh = b_h[col];
#pragma unroll
            for (int q = 0; q < 4; ++q) {
                int row = rbase + m * 16 + (lane >> 4) * 4 + q;
                size_t off = (size_t)row * H_DIM + col;
                float hp = h_prev[off];
                float u = 1.0f / (1.0f + __expf(-(accu[m][n][q] + bu)));
                float cpre = accc[m][n][q] + bh;
                cpre = fminf(fmaxf(cpre, -15.0f), 15.0f);
                float e = __expf(2.0f * cpre);
                float c = (e - 1.0f) / (e + 1.0f);
                float h = hp + u * (c - hp);
                out[off] = h;
                out[BH + off] = h;
            }
        }
}

extern "C" void kernel_launch(void* const* d_in, const int* in_sizes, int n_in,
                              void* d_out, int out_size, void* d_ws, size_t ws_size,
                              hipStream_t stream) {
    const float* x      = (const float*)d_in[0];
    const float* h_prev = (const float*)d_in[1];
    const float* W_u    = (const float*)d_in[2];
    const float* b_u    = (const float*)d_in[3];
    const float* W_r    = (const float*)d_in[4];
    const float* b_r    = (const float*)d_in[5];
    const float* W_hx   = (const float*)d_in[6];
    const float* W_hh   = (const float*)d_in[7];
    const float* b_h    = (const float*)d_in[8];
    float* out = (float*)d_out;

    if (ws_size >= WS2_NEED_BYTES) {
        unsigned short* ws = (unsigned short*)d_ws;
        hipLaunchKernelGGL(k_conv, dim3(2048), dim3(256), 0, stream,
                           x, h_prev, W_u, W_hx, W_hh, W_r, ws);
        hipLaunchKernelGGL(k_gates_b, dim3(2048), dim3(256), 0, stream,
                           ws + OFF_HB, ws + OFF_WR, ws + OFF_WU, b_r, b_u,
                           ws + OFF_A2 + 512, ws + OFF_U16);
        hipLaunchKernelGGL(k_cand_b, dim3(1024), dim3(256), 0, stream,
                           ws + OFF_A2, ws + OFF_W2, ws + OFF_HB, ws + OFF_U16,
                           b_h, out);
    } else {
        unsigned short* rh = (unsigned short*)d_ws;
        hipLaunchKernelGGL(k_rgate, dim3(1024), dim3(256), 0, stream, h_prev, W_r, b_r, rh);
        hipLaunchKernelGGL(k_fused, dim3(1024), dim3(256), 0, stream,
                           x, h_prev, W_u, b_u, W_hx, W_hh, b_h, rh, out);
    }
}

// Round 7
// 186.816 us; speedup vs baseline: 1.5379x; 1.1060x over previous
//
#include <hip/hip_runtime.h>
#include <hip/hip_bf16.h>

#define M_DIM 16384
#define IN_DIM 512
#define H_DIM 1024
#define BH (M_DIM * H_DIM)
#define K2 1536                            // fused K for cand: 512 (x) + 1024 (rh)

typedef float f32x4 __attribute__((ext_vector_type(4)));
typedef short bf16x8 __attribute__((ext_vector_type(8)));

// ---------------- bf16 helpers ----------------
static __device__ __forceinline__ unsigned short f2bf(float f) {
    union { float f; unsigned u; } a; a.f = f;
    unsigned r = a.u + 0x7fffu + ((a.u >> 16) & 1u);  // RNE
    return (unsigned short)(r >> 16);
}
static __device__ __forceinline__ float bf2f(unsigned short u) {
    union { unsigned u; float f; } a; a.u = (unsigned)u << 16;
    return a.f;
}

// ===================================================================
// ws layout (bf16 elements), total 124.78 MB
// ===================================================================
#define OFF_HB   0u                        // 16384x1024
#define OFF_A2   16777216u                 // 16384x1536: cols 0-511 = x, 512-1535 = rh
#define OFF_WU   41943040u                 // 1024x1024
#define OFF_WR   42991616u                 // 1024x1024
#define OFF_W2   44040192u                 // 1024x1536: cols 0-511 = W_hx, 512-1535 = W_hh
#define OFF_U16  45613056u                 // 16384x1024
#define WS2_ELEMS 62390272u
#define WS2_NEED_BYTES (WS2_ELEMS * 2ull)

// One-pass fp32 -> bf16 conversion of all operands into the fused layout.
__global__ __launch_bounds__(256) void k_conv(const float* __restrict__ x,
                                              const float* __restrict__ h,
                                              const float* __restrict__ wu,
                                              const float* __restrict__ whx,
                                              const float* __restrict__ whh,
                                              const float* __restrict__ wr,
                                              unsigned short* __restrict__ ws) {
    const int total = 3604480;  // total 8-elem units
    for (int u = blockIdx.x * blockDim.x + threadIdx.x; u < total;
         u += gridDim.x * blockDim.x) {
        const float* src; unsigned short* d; int lu;
        if (u < 2097152)      { lu = u;
                                src = h + (size_t)lu * 8;
                                d = ws + OFF_HB + (size_t)lu * 8; }
        else if (u < 3145728) { lu = u - 2097152;                       // x -> A2 strided
                                src = x + (size_t)lu * 8;
                                d = ws + OFF_A2 + (size_t)(lu >> 6) * K2 + (lu & 63) * 8; }
        else if (u < 3276800) { lu = u - 3145728;
                                src = wu + (size_t)lu * 8;
                                d = ws + OFF_WU + (size_t)lu * 8; }
        else if (u < 3342336) { lu = u - 3276800;                       // whx -> W2 strided
                                src = whx + (size_t)lu * 8;
                                d = ws + OFF_W2 + (size_t)(lu >> 6) * K2 + (lu & 63) * 8; }
        else if (u < 3473408) { lu = u - 3342336;                       // whh -> W2 + 512
                                src = whh + (size_t)lu * 8;
                                d = ws + OFF_W2 + (size_t)(lu >> 7) * K2 + 512 + (lu & 127) * 8; }
        else                  { lu = u - 3473408;
                                src = wr + (size_t)lu * 8;
                                d = ws + OFF_WR + (size_t)lu * 8; }
        float4 a = *reinterpret_cast<const float4*>(src);
        float4 b = *reinterpret_cast<const float4*>(src + 4);
        uint4 p;
        p.x = (unsigned)f2bf(a.x) | ((unsigned)f2bf(a.y) << 16);
        p.y = (unsigned)f2bf(a.z) | ((unsigned)f2bf(a.w) << 16);
        p.z = (unsigned)f2bf(b.x) | ((unsigned)f2bf(b.y) << 16);
        p.w = (unsigned)f2bf(b.z) | ((unsigned)f2bf(b.w) << 16);
        *reinterpret_cast<uint4*>(d) = p;
    }
}

// Stage a 128x64 bf16 tile into linear LDS via global_load_lds width-16, with the
// chunk-column involution kc ^ (row&7) applied on the GLOBAL side (rule #21).
static __device__ __forceinline__ void stage_lds(const unsigned short* __restrict__ src,
                                                 int rowBase, int ld, int ks,
                                                 unsigned short* lds, int tid) {
#pragma unroll
    for (int i = 0; i < 4; ++i) {
        int c = i * 256 + tid;           // 16B-chunk id in [0,1024): 128 rows x 8 chunks
        int r = c >> 3, kc = c & 7;
        int gc = kc ^ (r & 7);           // involution
        const unsigned short* g = src + (size_t)(rowBase + r) * ld + ks + gc * 8;
        unsigned short* l = lds + c * 8;
        __builtin_amdgcn_global_load_lds((const __attribute__((address_space(1))) void*)g,
                                         (__attribute__((address_space(3))) void*)l,
                                         16, 0, 0);
    }
}

// One GEMM segment (proven r2/r3 structure): C[128x128] += A x B^T, BK=64.
template <int KSEG>
static __device__ __forceinline__ void gemm_seg(const unsigned short* __restrict__ A, int aLd,
                                                const unsigned short* __restrict__ B, int bLd,
                                                int bm, int bn,
                                                unsigned short* As, unsigned short* Bs,
                                                int tid, int wm, int wn, int frow, int klane,
                                                f32x4 acc[4][4]) {
    for (int ks = 0; ks < KSEG; ks += 64) {
        stage_lds(A, bm * 128, aLd, ks, As, tid);
        stage_lds(B, bn * 128, bLd, ks, Bs, tid);
        __syncthreads();
#pragma unroll
        for (int kk = 0; kk < 2; ++kk) {
            bf16x8 av[4], bv[4];
#pragma unroll
            for (int m = 0; m < 4; ++m) {
                int pr = wm * 64 + m * 16 + frow;
                av[m] = *reinterpret_cast<const bf16x8*>(
                    &As[pr * 64 + (((kk << 2) + klane) ^ (pr & 7)) * 8]);
            }
#pragma unroll
            for (int n = 0; n < 4; ++n) {
                int pr = wn * 64 + n * 16 + frow;
                bv[n] = *reinterpret_cast<const bf16x8*>(
                    &Bs[pr * 64 + (((kk << 2) + klane) ^ (pr & 7)) * 8]);
            }
#pragma unroll
            for (int m = 0; m < 4; ++m)
#pragma unroll
                for (int n = 0; n < 4; ++n)
                    acc[m][n] = __builtin_amdgcn_mfma_f32_16x16x32_bf16(av[m], bv[n], acc[m][n], 0, 0, 0);
        }
        __syncthreads();
    }
}

// r-gate GEMM (nwg=1024, proven config): rh = bf16(sigmoid(hb@wr^T + b_r) * hb),
// written STRIDED into A2 col 512+ (so cand stays single-segment K=1536).
__global__ __launch_bounds__(256, 3) void k_rgate_s(const unsigned short* __restrict__ hb,
                                                    const unsigned short* __restrict__ wrb,
                                                    const float* __restrict__ b_r,
                                                    unsigned short* __restrict__ rhA2) {
    __shared__ unsigned short As[128 * 64];
    __shared__ unsigned short Bs[128 * 64];

    int bid = blockIdx.x;
    int swz = (bid & 7) * 128 + (bid >> 3);   // bijective XCD swizzle, nwg=1024
    int bm = swz >> 3, bn = swz & 7;

    int tid = threadIdx.x;
    int wave = tid >> 6, lane = tid & 63;
    int wm = wave >> 1, wn = wave & 1;
    int frow = lane & 15, klane = lane >> 4;

    f32x4 acc[4][4] = {};
    gemm_seg<H_DIM>(hb, H_DIM, wrb, H_DIM, bm, bn, As, Bs, tid, wm, wn, frow, klane, acc);

    int rbase = bm * 128 + wm * 64;
    int cbase = bn * 128 + wn * 64;
#pragma unroll
    for (int m = 0; m < 4; ++m) {
#pragma unroll
        for (int n = 0; n < 4; ++n) {
            int col = cbase + n * 16 + frow;
            float bs = b_r[col];
#pragma unroll
            for (int q = 0; q < 4; ++q) {
                int row = rbase + m * 16 + klane * 4 + q;
                float g = 1.0f / (1.0f + __expf(-(acc[m][n][q] + bs)));
                rhA2[(size_t)row * K2 + col] = f2bf(g * bf2f(hb[(size_t)row * H_DIM + col]));
            }
        }
    }
}

// u-gate GEMM (nwg=1024): u16 = bf16(sigmoid(hb@wu^T + b_u)), linear.
__global__ __launch_bounds__(256, 3) void k_ugate_s(const unsigned short* __restrict__ hb,
                                                    const unsigned short* __restrict__ wub,
                                                    const float* __restrict__ b_u,
                                                    unsigned short* __restrict__ u16) {
    __shared__ unsigned short As[128 * 64];
    __shared__ unsigned short Bs[128 * 64];

    int bid = blockIdx.x;
    int swz = (bid & 7) * 128 + (bid >> 3);   // bijective XCD swizzle, nwg=1024
    int bm = swz >> 3, bn = swz & 7;

    int tid = threadIdx.x;
    int wave = tid >> 6, lane = tid & 63;
    int wm = wave >> 1, wn = wave & 1;
    int frow = lane & 15, klane = lane >> 4;

    f32x4 acc[4][4] = {};
    gemm_seg<H_DIM>(hb, H_DIM, wub, H_DIM, bm, bn, As, Bs, tid, wm, wn, frow, klane, acc);

    int rbase = bm * 128 + wm * 64;
    int cbase = bn * 128 + wn * 64;
#pragma unroll
    for (int m = 0; m < 4; ++m) {
#pragma unroll
        for (int n = 0; n < 4; ++n) {
            int col = cbase + n * 16 + frow;
            float bs = b_u[col];
#pragma unroll
            for (int q = 0; q < 4; ++q) {
                int row = rbase + m * 16 + klane * 4 + q;
                float g = 1.0f / (1.0f + __expf(-(acc[m][n][q] + bs)));
                u16[(size_t)row * H_DIM + col] = f2bf(g);
            }
        }
    }
}

// Candidate GEMM + blend: single segment, A2=[x|rh] (ld 1536) x W2=[Whx|Whh]^T.
__global__ __launch_bounds__(256, 3) void k_cand_b(const unsigned short* __restrict__ a2,
                                                   const unsigned short* __restrict__ w2,
                                                   const unsigned short* __restrict__ hb,
                                                   const unsigned short* __restrict__ u16,
                                                   const float* __restrict__ b_h,
                                                   float* __restrict__ out) {
    __shared__ unsigned short As[128 * 64];
    __shared__ unsigned short Bs[128 * 64];

    int bid = blockIdx.x;
    int swz = (bid & 7) * 128 + (bid >> 3);   // bijective XCD swizzle, nwg=1024
    int bm = swz >> 3, bn = swz & 7;

    int tid = threadIdx.x;
    int wave = tid >> 6, lane = tid & 63;
    int wm = wave >> 1, wn = wave & 1;
    int frow = lane & 15, klane = lane >> 4;

    f32x4 acc[4][4] = {};
    gemm_seg<K2>(a2, K2, w2, K2, bm, bn, As, Bs, tid, wm, wn, frow, klane, acc);

    int rbase = bm * 128 + wm * 64;
    int cbase = bn * 128 + wn * 64;
#pragma unroll
    for (int m = 0; m < 4; ++m) {
#pragma unroll
        for (int n = 0; n < 4; ++n) {
            int col = cbase + n * 16 + frow;
            float bh = b_h[col];
#pragma unroll
            for (int q = 0; q < 4; ++q) {
                int row = rbase + m * 16 + klane * 4 + q;
                size_t off = (size_t)row * H_DIM + col;
                float hp = bf2f(hb[off]);
                float u = bf2f(u16[off]);
                float cpre = acc[m][n][q] + bh;
                cpre = fminf(fmaxf(cpre, -15.0f), 15.0f);
                float e = __expf(2.0f * cpre);
                float c = (e - 1.0f) / (e + 1.0f);
                float h = hp + u * (c - hp);
                out[off] = h;
                out[BH + off] = h;
            }
        }
    }
}

// ===================================================================
// FALLBACK PATH (round-1 kernels, fp32 reg-staged) — used if ws too small
// ===================================================================
#define LDSS 40

static __device__ __forceinline__ void stage_f32(const float* __restrict__ src, int rowBase,
                                                 int ld, int kBase,
                                                 unsigned short* lds, int tid) {
#pragma unroll
    for (int i = 0; i < 4; ++i) {
        int idx = i * 256 + tid;
        int r = idx >> 3, c4 = idx & 7;
        const float4 v = *reinterpret_cast<const float4*>(
            src + (size_t)(rowBase + r) * ld + kBase + c4 * 4);
        uint2 p;
        p.x = (unsigned)f2bf(v.x) | ((unsigned)f2bf(v.y) << 16);
        p.y = (unsigned)f2bf(v.z) | ((unsigned)f2bf(v.w) << 16);
        *reinterpret_cast<uint2*>(lds + r * LDSS + c4 * 4) = p;
    }
}

static __device__ __forceinline__ void stage_bf16s(const unsigned short* __restrict__ src,
                                                   int rowBase, int ld, int kBase,
                                                   unsigned short* lds, int tid) {
#pragma unroll
    for (int i = 0; i < 2; ++i) {
        int idx = i * 256 + tid;
        int r = idx >> 2, c8 = idx & 3;
        const uint4 v = *reinterpret_cast<const uint4*>(
            src + (size_t)(rowBase + r) * ld + kBase + c8 * 8);
        *reinterpret_cast<uint4*>(lds + r * LDSS + c8 * 8) = v;
    }
}

__global__ __launch_bounds__(256, 2) void k_rgate(const float* __restrict__ h_prev,
                                                  const float* __restrict__ W_r,
                                                  const float* __restrict__ b_r,
                                                  unsigned short* __restrict__ rh) {
    __shared__ unsigned short As[128 * LDSS];
    __shared__ unsigned short Bs[128 * LDSS];
    int bid = blockIdx.x;
    int swz = (bid & 7) * 128 + (bid >> 3);
    int bm = swz >> 3, bn = swz & 7;
    int tid = threadIdx.x;
    int wave = tid >> 6, lane = tid & 63;
    int wm = wave >> 1, wn = wave & 1;
    int frow = lane & 15, koff = (lane >> 4) * 8;
    f32x4 acc[4][4] = {};
    for (int ks = 0; ks < H_DIM; ks += 32) {
        stage_f32(h_prev, bm * 128, H_DIM, ks, As, tid);
        stage_f32(W_r, bn * 128, H_DIM, ks, Bs, tid);
        __syncthreads();
        bf16x8 av[4], bv[4];
#pragma unroll
        for (int m = 0; m < 4; ++m)
            av[m] = *reinterpret_cast<const bf16x8*>(&As[(wm * 64 + m * 16 + frow) * LDSS + koff]);
#pragma unroll
        for (int n = 0; n < 4; ++n)
            bv[n] = *reinterpret_cast<const bf16x8*>(&Bs[(wn * 64 + n * 16 + frow) * LDSS + koff]);
#pragma unroll
        for (int m = 0; m < 4; ++m)
#pragma unroll
            for (int n = 0; n < 4; ++n)
                acc[m][n] = __builtin_amdgcn_mfma_f32_16x16x32_bf16(av[m], bv[n], acc[m][n], 0, 0, 0);
        __syncthreads();
    }
    int rbase = bm * 128 + wm * 64, cbase = bn * 128 + wn * 64;
#pragma unroll
    for (int m = 0; m < 4; ++m)
#pragma unroll
        for (int n = 0; n < 4; ++n) {
            int col = cbase + n * 16 + frow;
            float bias = b_r[col];
#pragma unroll
            for (int q = 0; q < 4; ++q) {
                int row = rbase + m * 16 + (lane >> 4) * 4 + q;
                float pre = acc[m][n][q] + bias;
                float rv = 1.0f / (1.0f + __expf(-pre));
                rh[(size_t)row * H_DIM + col] = f2bf(rv * h_prev[(size_t)row * H_DIM + col]);
            }
        }
}

__global__ __launch_bounds__(256, 2) void k_fused(const float* __restrict__ x,
                                                  const float* __restrict__ h_prev,
                                                  const float* __restrict__ W_u,
                                                  const float* __restrict__ b_u,
                                                  const float* __restrict__ W_hx,
                                                  const float* __restrict__ W_hh,
                                                  const float* __restrict__ b_h,
                                                  const unsigned short* __restrict__ rh,
                                                  float* __restrict__ out) {
    __shared__ unsigned short As[128 * LDSS];
    __shared__ unsigned short Bs[128 * LDSS];
    int bid = blockIdx.x;
    int swz = (bid & 7) * 128 + (bid >> 3);
    int bm = swz >> 3, bn = swz & 7;
    int tid = threadIdx.x;
    int wave = tid >> 6, lane = tid & 63;
    int wm = wave >> 1, wn = wave & 1;
    int frow = lane & 15, koff = (lane >> 4) * 8;
    f32x4 accu[4][4] = {};
    f32x4 accc[4][4] = {};
    for (int ks = 0; ks < H_DIM; ks += 32) {
        stage_f32(h_prev, bm * 128, H_DIM, ks, As, tid);
        stage_f32(W_u, bn * 128, H_DIM, ks, Bs, tid);
        __syncthreads();
        bf16x8 av[4], bv[4];
#pragma unroll
        for (int m = 0; m < 4; ++m)
            av[m] = *reinterpret_cast<const bf16x8*>(&As[(wm * 64 + m * 16 + frow) * LDSS + koff]);
#pragma unroll
        for (int n = 0; n < 4; ++n)
            bv[n] = *reinterpret_cast<const bf16x8*>(&Bs[(wn * 64 + n * 16 + frow) * LDSS + koff]);
#pragma unroll
        for (int m = 0; m < 4; ++m)
#pragma unroll
            for (int n = 0; n < 4; ++n)
                accu[m][n] = __builtin_amdgcn_mfma_f32_16x16x32_bf16(av[m], bv[n], accu[m][n], 0, 0, 0);
        __syncthreads();
    }
    for (int ks = 0; ks < IN_DIM; ks += 32) {
        stage_f32(x, bm * 128, IN_DIM, ks, As, tid);
        stage_f32(W_hx, bn * 128, IN_DIM, ks, Bs, tid);
        __syncthreads();
        bf16x8 av[4], bv[4];
#pragma unroll
        for (int m = 0; m < 4; ++m)
            av[m] = *reinterpret_cast<const bf16x8*>(&As[(wm * 64 + m * 16 + frow) * LDSS + koff]);
#pragma unroll
        for (int n = 0; n < 4; ++n)
            bv[n] = *reinterpret_cast<const bf16x8*>(&Bs[(wn * 64 + n * 16 + frow) * LDSS + koff]);
#pragma unroll
        for (int m = 0; m < 4; ++m)
#pragma unroll
            for (int n = 0; n < 4; ++n)
                accc[m][n] = __builtin_amdgcn_mfma_f32_16x16x32_bf16(av[m], bv[n], accc[m][n], 0, 0, 0);
        __syncthreads();
    }
    for (int ks = 0; ks < H_DIM; ks += 32) {
        stage_bf16s(rh, bm * 128, H_DIM, ks, As, tid);
        stage_f32(W_hh, bn * 128, H_DIM, ks, Bs, tid);
        __syncthreads();
        bf16x8 av[4], bv[4];
#pragma unroll
        for (int m = 0; m < 4; ++m)
            av[m] = *reinterpret_cast<const bf16x8*>(&As[(wm * 64 + m * 16 + frow) * LDSS + koff]);
#pragma unroll
        for (int n = 0; n < 4; ++n)
            bv[n] = *reinterpret_cast<const bf16x8*>(&Bs[(wn * 64 + n * 16 + frow) * LDSS + koff]);
#pragma unroll
        for (int m = 0; m < 4; ++m)
#pragma unroll
            for (int n = 0; n < 4; ++n)
                accc[m][n] = __builtin_amdgcn_mfma_f32_16x16x32_bf16(av[m], bv[n], accc[m][n], 0, 0, 0);
        __syncthreads();
    }
    int rbase = bm * 128 + wm * 64, cbase = bn * 128 + wn * 64;
#pragma unroll
    for (int m = 0; m < 4; ++m)
#pragma unroll
        for (int n = 0; n < 4; ++n) {
            int col = cbase + n * 16 + frow;
            float bu = b_u[col], bh = b_h[col];
#pragma unroll
            for (int q = 0; q < 4; ++q) {
                int row = rbase + m * 16 + (lane >> 4) * 4 + q;
                size_t off = (size_t)row * H_DIM + col;
                float hp = h_prev[off];
                float u = 1.0f / (1.0f + __expf(-(accu[m][n][q] + bu)));
                float cpre = accc[m][n][q] + bh;
                cpre = fminf(fmaxf(cpre, -15.0f), 15.0f);
                float e = __expf(2.0f * cpre);
                float c = (e - 1.0f) / (e + 1.0f);
                float h = hp + u * (c - hp);
                out[off] = h;
                out[BH + off] = h;
            }
        }
}

extern "C" void kernel_launch(void* const* d_in, const int* in_sizes, int n_in,
                              void* d_out, int out_size, void* d_ws, size_t ws_size,
                              hipStream_t stream) {
    const float* x      = (const float*)d_in[0];
    const float* h_prev = (const float*)d_in[1];
    const float* W_u    = (const float*)d_in[2];
    const float* b_u    = (const float*)d_in[3];
    const float* W_r    = (const float*)d_in[4];
    const float* b_r    = (const float*)d_in[5];
    const float* W_hx   = (const float*)d_in[6];
    const float* W_hh   = (const float*)d_in[7];
    const float* b_h    = (const float*)d_in[8];
    float* out = (float*)d_out;

    if (ws_size >= WS2_NEED_BYTES) {
        unsigned short* ws = (unsigned short*)d_ws;
        hipLaunchKernelGGL(k_conv, dim3(2048), dim3(256), 0, stream,
                           x, h_prev, W_u, W_hx, W_hh, W_r, ws);
        hipLaunchKernelGGL(k_rgate_s, dim3(1024), dim3(256), 0, stream,
                           ws + OFF_HB, ws + OFF_WR, b_r, ws + OFF_A2 + 512);
        hipLaunchKernelGGL(k_ugate_s, dim3(1024), dim3(256), 0, stream,
                           ws + OFF_HB, ws + OFF_WU, b_u, ws + OFF_U16);
        hipLaunchKernelGGL(k_cand_b, dim3(1024), dim3(256), 0, stream,
                           ws + OFF_A2, ws + OFF_W2, ws + OFF_HB, ws + OFF_U16,
                           b_h, out);
    } else {
        unsigned short* rh = (unsigned short*)d_ws;
        hipLaunchKernelGGL(k_rgate, dim3(1024), dim3(256), 0, stream, h_prev, W_r, b_r, rh);
        hipLaunchKernelGGL(k_fused, dim3(1024), dim3(256), 0, stream,
                           x, h_prev, W_u, b_u, W_hx, W_hh, b_h, rh, out);
    }
}